// Round 1
// baseline (1234.324 us; speedup 1.0000x reference)
//
#include <hip/hip_runtime.h>
#include <hip/hip_bf16.h>

typedef __hip_bfloat16 bf16;
typedef __attribute__((ext_vector_type(8))) short short8;
typedef __attribute__((ext_vector_type(4))) float floatx4;

#define NB 32
#define NC 512
#define ND 512
#define NDH 64
#define NFF 2048
#define KW 7

__device__ __forceinline__ float bf2f(bf16 v) { return __bfloat162float(v); }
__device__ __forceinline__ bf16 f2bf(float f) { return __float2bfloat16(f); }
__device__ __forceinline__ float ldf(const float* p) { return *p; }
__device__ __forceinline__ float ldf(const bf16* p) { return __bfloat162float(*p); }

// ---- conv-weight transpose: W (512,512,7) f32 -> Wt[tap][co][ci] bf16
__global__ __launch_bounds__(256) void k_transpose_w(const float* __restrict__ w,
                                                     bf16* __restrict__ wt) {
  int idx = blockIdx.x * 256 + threadIdx.x;
  if (idx >= NC * NC) return;
  int co = idx >> 9, ci = idx & 511;
#pragma unroll
  for (int t = 0; t < KW; ++t)
    wt[(size_t)t * NC * NC + co * NC + ci] = f2bf(w[(size_t)co * NC * KW + (size_t)ci * KW + t]);
}

// ---- 2D transpose f32 -> bf16 : dst[c][r] = src[r][c]; R,C multiples of 32
__global__ __launch_bounds__(256) void k_transpose2d(const float* __restrict__ src,
                                                     bf16* __restrict__ dst,
                                                     int R, int Ccols) {
  __shared__ bf16 t[32][33];
  int bc = blockIdx.x * 32, br = blockIdx.y * 32;
  int tx = threadIdx.x & 31, ty = threadIdx.x >> 5;
#pragma unroll
  for (int i = 0; i < 32; i += 8)
    t[ty + i][tx] = f2bf(src[(size_t)(br + ty + i) * Ccols + bc + tx]);
  __syncthreads();
#pragma unroll
  for (int i = 0; i < 32; i += 8)
    dst[(size_t)(bc + ty + i) * R + br + tx] = t[tx][ty + i];
}

// ---- causal conv over last axis as 7-tap shifted GEMM.
// Y[b,co,d] = outScale * ( sum_{tap,ci} Wt[tap][co][ci] * X[b,ci,d-6+tap] + bias[co] )
// Block: 128(co) x 128(d) tile, 4 waves (2x2, 64x64 each). A-frags direct from global
// (Wt is ci-contiguous, L2-resident). B staged transposed in LDS: Bs[r][ci], r -> d0-6+r.
template <typename TIN>
__global__ __launch_bounds__(256, 2) void k_conv(const TIN* __restrict__ X,
                                                 const bf16* __restrict__ Wt,
                                                 const float* __restrict__ bias,
                                                 bf16* __restrict__ Y, float outScale) {
  __shared__ __align__(16) bf16 Bs[136][40];  // 134 rows used; pad-40 stride -> ~2-way banks
  const int d0 = blockIdx.x * 128;
  const int co0 = blockIdx.y * 128;
  const int b = blockIdx.z;
  const int tid = threadIdx.x;
  const int lane = tid & 63, wave = tid >> 6;
  const int wm = (wave & 1) * 64, wn = (wave >> 1) * 64;
  const int m16 = lane & 15, qd = lane >> 4;

  floatx4 acc[4][4];
  const floatx4 zero = {0.f, 0.f, 0.f, 0.f};
#pragma unroll
  for (int i = 0; i < 4; ++i)
#pragma unroll
    for (int j = 0; j < 4; ++j) acc[i][j] = zero;

  const TIN* xb = X + (size_t)b * NC * ND;

  for (int cs = 0; cs < NC / 32; ++cs) {
    __syncthreads();
    for (int f = tid; f < 134 * 32; f += 256) {
      int r = f % 134, c = f / 134;
      int d = d0 - 6 + r;
      Bs[r][c] = (d >= 0) ? f2bf(ldf(xb + (size_t)(cs * 32 + c) * ND + d)) : f2bf(0.f);
    }
    __syncthreads();
    const bf16* wbase = Wt + (size_t)co0 * NC + cs * 32;
#pragma unroll
    for (int tap = 0; tap < KW; ++tap) {
      const bf16* wt = wbase + (size_t)tap * NC * NC;
      short8 a[4];
#pragma unroll
      for (int im = 0; im < 4; ++im)
        a[im] = *reinterpret_cast<const short8*>(wt + (size_t)(wm + im * 16 + m16) * NC + qd * 8);
#pragma unroll
      for (int jn = 0; jn < 4; ++jn) {
        short8 bfr = *reinterpret_cast<const short8*>(&Bs[wn + jn * 16 + m16 + tap][qd * 8]);
#pragma unroll
        for (int im = 0; im < 4; ++im)
          acc[im][jn] = __builtin_amdgcn_mfma_f32_16x16x32_bf16(a[im], bfr, acc[im][jn], 0, 0, 0);
      }
    }
  }
  bf16* yb = Y + (size_t)b * NC * ND;
#pragma unroll
  for (int im = 0; im < 4; ++im) {
    int cobase = co0 + wm + im * 16 + qd * 4;
#pragma unroll
    for (int jn = 0; jn < 4; ++jn) {
      int d = d0 + wn + jn * 16 + m16;
#pragma unroll
      for (int r = 0; r < 4; ++r) {
        float v = (acc[im][jn][r] + bias[cobase + r]) * outScale;
        yb[(size_t)(cobase + r) * ND + d] = f2bf(v);
      }
    }
  }
}

// ---- layernorm over last dim (512); unbiased var; y = g*(x-mean)/(sqrt(var)+eps)+b
__global__ __launch_bounds__(256, 4) void k_layernorm(const bf16* __restrict__ x,
                                                      const float* __restrict__ gamma,
                                                      const float* __restrict__ beta,
                                                      bf16* __restrict__ y) {
  int row = blockIdx.x * 4 + (threadIdx.x >> 6);
  int lane = threadIdx.x & 63;
  const bf16* xr = x + (size_t)row * ND + lane * 8;
  uint4 raw = *reinterpret_cast<const uint4*>(xr);
  const bf16* rp = reinterpret_cast<const bf16*>(&raw);
  float v[8];
#pragma unroll
  for (int j = 0; j < 8; ++j) v[j] = bf2f(rp[j]);
  float s = 0.f;
#pragma unroll
  for (int j = 0; j < 8; ++j) s += v[j];
#pragma unroll
  for (int m = 32; m >= 1; m >>= 1) s += __shfl_xor(s, m, 64);
  float mean = s * (1.f / 512.f);
  float ss = 0.f;
#pragma unroll
  for (int j = 0; j < 8; ++j) { float dd = v[j] - mean; ss += dd * dd; }
#pragma unroll
  for (int m = 32; m >= 1; m >>= 1) ss += __shfl_xor(ss, m, 64);
  float rden = 1.f / (sqrtf(ss * (1.f / 511.f)) + 1e-6f);
  __align__(16) bf16 outv[8];
#pragma unroll
  for (int j = 0; j < 8; ++j)
    outv[j] = f2bf(gamma[lane * 8 + j] * (v[j] - mean) * rden + beta[lane * 8 + j]);
  *reinterpret_cast<uint4*>(y + (size_t)row * ND + lane * 8) = *reinterpret_cast<uint4*>(outv);
}

// ---- flash-style attention. Block = (qchunk 128, head, batch); 4 waves, 32 q-rows each.
// No max-subtraction (scores O(+-5) at this scale); l accumulated per row, O normalized at end.
__global__ __launch_bounds__(256, 2) void k_attention(const bf16* __restrict__ Q,
                                                      const bf16* __restrict__ K,
                                                      const bf16* __restrict__ V,
                                                      bf16* __restrict__ O) {
  __shared__ __align__(16) bf16 Ks[64][72];      // [key][dh]
  __shared__ __align__(16) bf16 Vt[64][72];      // [dh][key]
  __shared__ __align__(16) bf16 Ps[4][32][72];   // per-wave P chunk [qrow][key]
  const int qc = blockIdx.x, h = blockIdx.y, b = blockIdx.z;
  const int tid = threadIdx.x;
  const int lane = tid & 63, wave = tid >> 6;
  const int m16 = lane & 15, qd = lane >> 4;
  const size_t base = (size_t)b * NC * ND + (size_t)h * NDH;

  short8 aq[2][2];  // Q a-frags, loop-invariant
#pragma unroll
  for (int ms = 0; ms < 2; ++ms)
#pragma unroll
    for (int ks = 0; ks < 2; ++ks)
      aq[ms][ks] = *reinterpret_cast<const short8*>(
          Q + base + (size_t)(qc * 128 + wave * 32 + ms * 16 + m16) * ND + ks * 32 + qd * 8);

  floatx4 o_acc[2][4];
  const floatx4 zero = {0.f, 0.f, 0.f, 0.f};
#pragma unroll
  for (int i = 0; i < 2; ++i)
#pragma unroll
    for (int j = 0; j < 4; ++j) o_acc[i][j] = zero;
  float lsum[2][4];
#pragma unroll
  for (int i = 0; i < 2; ++i)
#pragma unroll
    for (int r = 0; r < 4; ++r) lsum[i][r] = 0.f;

  for (int kc = 0; kc < 8; ++kc) {
    __syncthreads();
    {
      int rr = tid >> 2, seg = (tid & 3) * 16;
      const bf16* src = K + base + (size_t)(kc * 64 + rr) * ND + seg;
      *reinterpret_cast<uint4*>(&Ks[rr][seg]) = *reinterpret_cast<const uint4*>(src);
      *reinterpret_cast<uint4*>(&Ks[rr][seg + 8]) = *reinterpret_cast<const uint4*>(src + 8);
      const bf16* vsrc = V + base + (size_t)(kc * 64 + rr) * ND + seg;
      __align__(16) bf16 tmp[16];
      *reinterpret_cast<uint4*>(&tmp[0]) = *reinterpret_cast<const uint4*>(vsrc);
      *reinterpret_cast<uint4*>(&tmp[8]) = *reinterpret_cast<const uint4*>(vsrc + 8);
#pragma unroll
      for (int i = 0; i < 16; ++i) Vt[seg + i][rr] = tmp[i];
    }
    __syncthreads();
    floatx4 s[2][4];
#pragma unroll
    for (int i = 0; i < 2; ++i)
#pragma unroll
      for (int j = 0; j < 4; ++j) s[i][j] = zero;
#pragma unroll
    for (int ks = 0; ks < 2; ++ks) {
#pragma unroll
      for (int ns = 0; ns < 4; ++ns) {
        short8 bk = *reinterpret_cast<const short8*>(&Ks[ns * 16 + m16][ks * 32 + qd * 8]);
#pragma unroll
        for (int ms = 0; ms < 2; ++ms)
          s[ms][ns] = __builtin_amdgcn_mfma_f32_16x16x32_bf16(aq[ms][ks], bk, s[ms][ns], 0, 0, 0);
      }
    }
#pragma unroll
    for (int ms = 0; ms < 2; ++ms)
#pragma unroll
      for (int ns = 0; ns < 4; ++ns)
#pragma unroll
        for (int r = 0; r < 4; ++r) {
          float p = __expf(s[ms][ns][r] * 0.125f);
          lsum[ms][r] += p;
          Ps[wave][ms * 16 + qd * 4 + r][ns * 16 + m16] = f2bf(p);
        }
#pragma unroll
    for (int ks = 0; ks < 2; ++ks) {
      short8 ap[2];
#pragma unroll
      for (int ms = 0; ms < 2; ++ms)
        ap[ms] = *reinterpret_cast<const short8*>(&Ps[wave][ms * 16 + m16][ks * 32 + qd * 8]);
#pragma unroll
      for (int ns = 0; ns < 4; ++ns) {
        short8 bv = *reinterpret_cast<const short8*>(&Vt[ns * 16 + m16][ks * 32 + qd * 8]);
#pragma unroll
        for (int ms = 0; ms < 2; ++ms)
          o_acc[ms][ns] = __builtin_amdgcn_mfma_f32_16x16x32_bf16(ap[ms], bv, o_acc[ms][ns], 0, 0, 0);
      }
    }
  }
#pragma unroll
  for (int ms = 0; ms < 2; ++ms)
#pragma unroll
    for (int r = 0; r < 4; ++r) {
      float t = lsum[ms][r];
      t += __shfl_xor(t, 1, 64);
      t += __shfl_xor(t, 2, 64);
      t += __shfl_xor(t, 4, 64);
      t += __shfl_xor(t, 8, 64);
      lsum[ms][r] = 1.f / t;
    }
#pragma unroll
  for (int ms = 0; ms < 2; ++ms) {
    int qrow = qc * 128 + wave * 32 + ms * 16 + qd * 4;
#pragma unroll
    for (int ns = 0; ns < 4; ++ns) {
      int dh = ns * 16 + m16;
#pragma unroll
      for (int r = 0; r < 4; ++r)
        O[base + (size_t)(qrow + r) * ND + dh] = f2bf(o_acc[ms][ns][r] * lsum[ms][r]);
    }
  }
}

// ---- GEMM C = A(MxK) * Bt(NxK)^T, both bf16 row-major k-contiguous.
// mode 0: Y(bf16) = relu(acc + bias[n]); mode 1: Y(f32) = 2*(acc + bias[n])
__global__ __launch_bounds__(256, 2) void k_gemm_bt(const bf16* __restrict__ A,
                                                    const bf16* __restrict__ Bt,
                                                    const float* __restrict__ bias,
                                                    void* __restrict__ Y,
                                                    int Kdim, int Ndim, int mode) {
  __shared__ __align__(16) bf16 As[128][40];
  __shared__ __align__(16) bf16 Bs[128][40];
  const int n0 = blockIdx.x * 128, m0 = blockIdx.y * 128;
  const int tid = threadIdx.x;
  const int lane = tid & 63, wave = tid >> 6;
  const int wm = (wave & 1) * 64, wn = (wave >> 1) * 64;
  const int m16 = lane & 15, qd = lane >> 4;
  floatx4 acc[4][4];
  const floatx4 zero = {0.f, 0.f, 0.f, 0.f};
#pragma unroll
  for (int i = 0; i < 4; ++i)
#pragma unroll
    for (int j = 0; j < 4; ++j) acc[i][j] = zero;
  const int row = tid >> 1, c0 = (tid & 1) * 16;
  for (int ks = 0; ks < Kdim / 32; ++ks) {
    __syncthreads();
    {
      const bf16* asrc = A + (size_t)(m0 + row) * Kdim + ks * 32 + c0;
      uint4 u0 = *reinterpret_cast<const uint4*>(asrc);
      uint4 u1 = *reinterpret_cast<const uint4*>(asrc + 8);
      const bf16* bsrc = Bt + (size_t)(n0 + row) * Kdim + ks * 32 + c0;
      uint4 w0 = *reinterpret_cast<const uint4*>(bsrc);
      uint4 w1 = *reinterpret_cast<const uint4*>(bsrc + 8);
      *reinterpret_cast<uint4*>(&As[row][c0]) = u0;
      *reinterpret_cast<uint4*>(&As[row][c0 + 8]) = u1;
      *reinterpret_cast<uint4*>(&Bs[row][c0]) = w0;
      *reinterpret_cast<uint4*>(&Bs[row][c0 + 8]) = w1;
    }
    __syncthreads();
    short8 a[4];
#pragma unroll
    for (int im = 0; im < 4; ++im)
      a[im] = *reinterpret_cast<const short8*>(&As[wm + im * 16 + m16][qd * 8]);
#pragma unroll
    for (int jn = 0; jn < 4; ++jn) {
      short8 bfr = *reinterpret_cast<const short8*>(&Bs[wn + jn * 16 + m16][qd * 8]);
#pragma unroll
      for (int im = 0; im < 4; ++im)
        acc[im][jn] = __builtin_amdgcn_mfma_f32_16x16x32_bf16(a[im], bfr, acc[im][jn], 0, 0, 0);
    }
  }
#pragma unroll
  for (int im = 0; im < 4; ++im) {
    int m = m0 + wm + im * 16 + qd * 4;
#pragma unroll
    for (int jn = 0; jn < 4; ++jn) {
      int n = n0 + wn + jn * 16 + m16;
      float bv = bias[n];
#pragma unroll
      for (int r = 0; r < 4; ++r) {
        float v = acc[im][jn][r] + bv;
        size_t idx = (size_t)(m + r) * Ndim + n;
        if (mode == 0) {
          ((bf16*)Y)[idx] = f2bf(fmaxf(v, 0.f));
        } else {
          ((float*)Y)[idx] = 2.f * v;
        }
      }
    }
  }
}

extern "C" void kernel_launch(void* const* d_in, const int* in_sizes, int n_in,
                              void* d_out, int out_size, void* d_ws, size_t ws_size,
                              hipStream_t stream) {
  (void)in_sizes; (void)n_in; (void)out_size; (void)ws_size;
  const float* x         = (const float*)d_in[0];
  const float* w_conv_in = (const float*)d_in[1];
  const float* b_conv_in = (const float*)d_in[2];
  const float* wq        = (const float*)d_in[3];
  const float* bq        = (const float*)d_in[4];
  const float* wk        = (const float*)d_in[5];
  const float* bk        = (const float*)d_in[6];
  const float* wv        = (const float*)d_in[7];
  const float* bv        = (const float*)d_in[8];
  const float* wo        = (const float*)d_in[9];
  const float* bo        = (const float*)d_in[10];
  const float* ln0_g     = (const float*)d_in[11];
  const float* ln0_b     = (const float*)d_in[12];
  const float* ln1_g     = (const float*)d_in[13];
  const float* ln1_b     = (const float*)d_in[14];
  const float* w1        = (const float*)d_in[15];
  const float* b1        = (const float*)d_in[16];
  const float* w2        = (const float*)d_in[17];
  const float* b2        = (const float*)d_in[18];

  char* ws = (char*)d_ws;
  const size_t WT  = (size_t)KW * NC * NC * 2;   // 3,670,016 B per conv weight
  const size_t W1T = (size_t)NFF * ND * 2;       // 2,097,152 B
  const size_t ACT = (size_t)NB * NC * ND * 2;   // 16,777,216 B
  size_t off = 0;
  bf16* wt_in = (bf16*)(ws + off); off += WT;
  bf16* wt_q  = (bf16*)(ws + off); off += WT;
  bf16* wt_k  = (bf16*)(ws + off); off += WT;
  bf16* wt_v  = (bf16*)(ws + off); off += WT;
  bf16* wt_o  = (bf16*)(ws + off); off += WT;
  bf16* w1t   = (bf16*)(ws + off); off += W1T;
  bf16* w2t   = (bf16*)(ws + off); off += W1T;
  bf16* bufA  = (bf16*)(ws + off); off += ACT;   // query_in, later reused for attn_o
  bf16* bufB  = (bf16*)(ws + off); off += ACT;   // xn, later h1
  bf16* bufC  = (bf16*)(ws + off); off += ACT;   // q, later hn
  bf16* bufD  = (bf16*)(ws + off); off += ACT;   // k
  bf16* bufE  = (bf16*)(ws + off); off += ACT;   // v
  bf16* mid   = (bf16*)(ws + off); off += (size_t)NB * NC * NFF * 2;  // ffn hidden

  // weight prep
  k_transpose_w<<<1024, 256, 0, stream>>>(w_conv_in, wt_in);
  k_transpose_w<<<1024, 256, 0, stream>>>(wq, wt_q);
  k_transpose_w<<<1024, 256, 0, stream>>>(wk, wt_k);
  k_transpose_w<<<1024, 256, 0, stream>>>(wv, wt_v);
  k_transpose_w<<<1024, 256, 0, stream>>>(wo, wt_o);
  k_transpose2d<<<dim3(NFF / 32, ND / 32), 256, 0, stream>>>(w1, w1t, ND, NFF);
  k_transpose2d<<<dim3(ND / 32, NFF / 32), 256, 0, stream>>>(w2, w2t, NFF, ND);

  dim3 cgrid(ND / 128, NC / 128, NB);
  // query_in = conv_in(x)
  k_conv<float><<<cgrid, 256, 0, stream>>>(x, wt_in, b_conv_in, bufA, 1.f);
  // xn = LN0(query_in)
  k_layernorm<<<NB * NC / 4, 256, 0, stream>>>(bufA, ln0_g, ln0_b, bufB);
  // q = conv(query_in, wq); k = conv(xn, wk); v = conv(xn, wv)
  k_conv<bf16><<<cgrid, 256, 0, stream>>>(bufA, wt_q, bq, bufC, 1.f);
  k_conv<bf16><<<cgrid, 256, 0, stream>>>(bufB, wt_k, bk, bufD, 1.f);
  k_conv<bf16><<<cgrid, 256, 0, stream>>>(bufB, wt_v, bv, bufE, 1.f);
  // attn_o (overwrites bufA; query_in no longer needed)
  k_attention<<<dim3(4, 8, NB), 256, 0, stream>>>(bufC, bufD, bufE, bufA);
  // h1 = 2*(conv(attn_o, wo) + bo)
  k_conv<bf16><<<cgrid, 256, 0, stream>>>(bufA, wt_o, bo, bufB, 2.f);
  // hn = LN1(h1)
  k_layernorm<<<NB * NC / 4, 256, 0, stream>>>(bufB, ln1_g, ln1_b, bufC);
  // ffn
  k_gemm_bt<<<dim3(NFF / 128, NB * NC / 128), 256, 0, stream>>>(bufC, w1t, b1, mid, ND, NFF, 0);
  k_gemm_bt<<<dim3(ND / 128, NB * NC / 128), 256, 0, stream>>>(mid, w2t, b2, d_out, NFF, ND, 1);
}